// Round 1
// 740.153 us; speedup vs baseline: 1.0226x; 1.0226x over previous
//
#include <hip/hip_runtime.h>
#include <math.h>

#define D      32000
#define BNUM   64
#define KNUM   4096
#define TN     64      // codebook rows per block
#define BK     64      // d-elements per stage
#define NSCB   (D / BK)                       // 500 column-blocks
#define AS_SCB 8192                           // ushorts per scb: 4ks*2lh*2hl*64row*8
#define AFMT_USHORTS ((size_t)NSCB * AS_SCB)  // 4,096,000
#define AFMT_BYTES   (AFMT_USHORTS * 2)       // 8,192,000 B

typedef __attribute__((ext_vector_type(8)))  short  short8;    // 8 bf16 (MFMA A/B frag)
typedef __attribute__((ext_vector_type(16))) float  floatx16;  // 32x32 MFMA acc

__device__ __forceinline__ unsigned short f32_bf16_rne(float f) {
    unsigned u = __float_as_uint(f);
    u += 0x7fff + ((u >> 16) & 1);          // round-to-nearest-even
    return (unsigned short)(u >> 16);
}
__device__ __forceinline__ float bf16_f32(unsigned short h) {
    return __uint_as_float(((unsigned)h) << 16);
}
__device__ __forceinline__ void cvt_hl(const float4 v, ushort4* h, ushort4* l) {
    h->x = f32_bf16_rne(v.x); l->x = f32_bf16_rne(v.x - bf16_f32(h->x));
    h->y = f32_bf16_rne(v.y); l->y = f32_bf16_rne(v.y - bf16_f32(h->y));
    h->z = f32_bf16_rne(v.z); l->z = f32_bf16_rne(v.z - bf16_f32(h->z));
    h->w = f32_bf16_rne(v.w); l->w = f32_bf16_rne(v.w - bf16_f32(h->w));
}

// lgkmcnt(0)-only barrier: global prefetch loads survive (no vmcnt drain).
__device__ __forceinline__ void barrier_lds() {
    __builtin_amdgcn_s_waitcnt(0xc07f);
    __builtin_amdgcn_s_barrier();
}

// ---------------------------------------------------------------------------
// Pre-convert latent (8 MB) into bf16 hi/lo MFMA-fragment order, ONCE.
// afmt[(((scb*4+ks)*2+lh)*2+hl)*512 + row*8 .. +8] = frag chunk for
// latent[row][scb*64 + ks*16 + lh*8 .. +8].  Writes fully coalesced.
// ---------------------------------------------------------------------------
__global__ __launch_bounds__(256) void conv_latent(
    const float* __restrict__ latent, unsigned short* __restrict__ afmt)
{
    const int t    = blockIdx.x * 256 + threadIdx.x;
    const int row  = t & 63;
    const int rest = t >> 6;                  // scb*8 + ks*2 + lh
    if (rest >= NSCB * 8) return;
    const int lh  = rest & 1;
    const int ks  = (rest >> 1) & 3;
    const int scb = rest >> 3;
    const float* src = latent + (size_t)row * D + scb * 64 + ks * 16 + lh * 8;
    const float4 v0 = *(const float4*)(src);
    const float4 v1 = *(const float4*)(src + 4);
    ushort4 h0, l0, h1, l1;
    cvt_hl(v0, &h0, &l0);
    cvt_hl(v1, &h1, &l1);
    unsigned short* d0 = afmt + ((size_t)(rest * 2 + 0) * 64 + row) * 8;  // hi
    unsigned short* d1 = afmt + ((size_t)(rest * 2 + 1) * 64 + row) * 8;  // lo
    *(ushort4*)(d0)     = h0;  *(ushort4*)(d0 + 4) = h1;
    *(ushort4*)(d1)     = l0;  *(ushort4*)(d1 + 4) = l1;
}

// ---------------------------------------------------------------------------
// xc[b][k] partials via bf16 hi/lo-split MFMA (3 products ~= fp32 exact),
// fused ||c||^2.  Block: 4 waves, tile 64(B) x 64(K); wave -> 32x32 quadrant.
//  - A frags: direct global->VGPR from pre-converted afmt (L2/LLC-resident).
//  - B: register prefetch 2 deep -> write-side cvt -> double-buffered LDS,
//    chunk-major layout with 1040B region stride: conflict-free reads+writes.
//  - ONE lgkm-only barrier per stage; vmcnt handled by register deps.
// ---------------------------------------------------------------------------
template<int NSTG>
__global__ __launch_bounds__(256, 4) void dist_mfma(
    const float* __restrict__ codebook, const unsigned short* __restrict__ afmt,
    float* __restrict__ ws_xc, float* __restrict__ ws_c2)
{
    // [buf][hi/lo][8 chunk-regions * 520 ushorts]  (region stride 1040 B)
    __shared__ __align__(16) unsigned short lds[2][2][8 * 520];   // 33,280 B

    const int tid  = threadIdx.x;
    const int k0   = blockIdx.x * TN;
    const int scb0 = blockIdx.y * NSTG;

    // B staging coords: thread covers rows rbase+16p, fp32 cols col4*4..+3
    const int col4 = tid & 15, rbase = tid >> 4;
    const int cc2  = col4 >> 1, half = col4 & 1;     // 16B-chunk, half-chunk
    const float* bptr = codebook + (size_t)(k0 + rbase) * D
                                 + (size_t)scb0 * 64 + col4 * 4;

    // MFMA coords
    const int wave = tid >> 6, lane = tid & 63;
    const int lr = lane & 31, lh = lane >> 5;
    const int mh = (wave & 1) * 32, nh = (wave >> 1) * 32;

    // A frag base: + s*AS_SCB + ks*2048 + hl*512 at load time
    const unsigned short* abase = afmt + (size_t)scb0 * AS_SCB
                                       + lh * 1024 + (mh + lr) * 8;
    // B frag LDS read offset: q*1040 + rb_off  (dense 16B stride: no conflicts)
    const int rb_off = lh * 520 + (nh + lr) * 8;

    floatx16 acc;
#pragma unroll
    for (int i = 0; i < 16; i++) acc[i] = 0.f;
    float c2p[4] = {0.f, 0.f, 0.f, 0.f};
    float4 pb[4];

#define LOADB(S)                                                               \
    {                                                                          \
        _Pragma("unroll")                                                      \
        for (int p = 0; p < 4; p++)                                            \
            pb[p] = *(const float4*)(bptr + (size_t)(16 * p) * D +             \
                                     (size_t)(S) * 64);                        \
    }

#define CVTWRITE(NB)                                                           \
    {                                                                          \
        _Pragma("unroll")                                                      \
        for (int p = 0; p < 4; p++) {                                          \
            c2p[p] += pb[p].x * pb[p].x + pb[p].y * pb[p].y +                  \
                      pb[p].z * pb[p].z + pb[p].w * pb[p].w;                   \
            ushort4 h, l;                                                      \
            cvt_hl(pb[p], &h, &l);                                             \
            const int wo = cc2 * 520 + (rbase + 16 * p) * 8 + half * 4;        \
            *(ushort4*)&lds[NB][0][wo] = h;                                    \
            *(ushort4*)&lds[NB][1][wo] = l;                                    \
        }                                                                      \
    }

    // prologue: B(0) -> buf0, B(1) staged in regs
    LOADB(0);
    CVTWRITE(0);
    LOADB(1);
    barrier_lds();

    for (int s = 0; s < NSTG; ++s) {
        // A fragments for stage s (8 x 16B global loads, cache-resident);
        // issued first so latency hides under the cvt/write phase below.
        short8 ah[4], al[4];
        const unsigned short* ap = abase + (size_t)s * AS_SCB;
#pragma unroll
        for (int q = 0; q < 4; q++) {
            ah[q] = *(const short8*)(ap + q * 2048);
            al[q] = *(const short8*)(ap + q * 2048 + 512);
        }
        // stage B(s+1) into the other buffer (safe: its readers passed the
        // previous barrier), then issue B(s+2) fetch.
        if (s + 1 < NSTG) CVTWRITE((s + 1) & 1);
        if (s + 2 < NSTG) LOADB(s + 2);
        // compute on buf[s&1]
        const int rbuf = s & 1;
#pragma unroll
        for (int q = 0; q < 4; q++) {
            const short8 bh = *(const short8*)&lds[rbuf][0][q * 1040 + rb_off];
            const short8 bl = *(const short8*)&lds[rbuf][1][q * 1040 + rb_off];
            acc = __builtin_amdgcn_mfma_f32_32x32x16_bf16(ah[q], bh, acc, 0,0,0);
            acc = __builtin_amdgcn_mfma_f32_32x32x16_bf16(ah[q], bl, acc, 0,0,0);
            acc = __builtin_amdgcn_mfma_f32_32x32x16_bf16(al[q], bh, acc, 0,0,0);
        }
        barrier_lds();
    }
#undef LOADB
#undef CVTWRITE

    // xc partials: C/D layout col=lane&31, row=(reg&3)+8*(reg>>2)+4*(lane>>5)
    const int split = blockIdx.y;
#pragma unroll
    for (int r = 0; r < 16; ++r) {
        const int row = (r & 3) + 8 * (r >> 2) + 4 * lh;
        const int b = mh + row;
        ws_xc[((size_t)split * BNUM + b) * KNUM + (k0 + nh + lr)] = acc[r];
    }

    // reduce ||c||^2 partials over the 16 lanes sharing a row group
#pragma unroll
    for (int p = 0; p < 4; ++p) {
        float v = c2p[p];
        v += __shfl_xor(v, 1);
        v += __shfl_xor(v, 2);
        v += __shfl_xor(v, 4);
        v += __shfl_xor(v, 8);
        if ((lane & 15) == 0)
            atomicAdd(ws_c2 + k0 + rbase + 16 * p, v);
    }
}

// ---------------------------------------------------------------------------
// Partial argmin: block (b, kc) handles k in [kc*256, (kc+1)*256); one k per
// thread, split-loads fully unrolled (independent -> ILP). 1024 blocks.
// ---------------------------------------------------------------------------
template<int DS>
__global__ __launch_bounds__(256) void argmin_part(
    const float* __restrict__ ws_xc, const float* __restrict__ ws_c2,
    float* __restrict__ ws_bscore, int* __restrict__ ws_bidx)
{
    const int b = blockIdx.x, kc = blockIdx.y, tid = threadIdx.x;
    const int k = kc * 256 + tid;
    float xc = 0.f;
#pragma unroll
    for (int s = 0; s < DS; s++)
        xc += ws_xc[((size_t)s * BNUM + b) * KNUM + k];
    __shared__ float sv[256];
    __shared__ int   si[256];
    sv[tid] = ws_c2[k] - 2.f * xc;
    si[tid] = k;
    __syncthreads();
    for (int off = 128; off > 0; off >>= 1) {
        if (tid < off) {
            const float ov = sv[tid + off];
            const int   oi = si[tid + off];
            if (ov < sv[tid] || (ov == sv[tid] && oi < si[tid])) {
                sv[tid] = ov; si[tid] = oi;
            }
        }
        __syncthreads();
    }
    if (tid == 0) { ws_bscore[b * 16 + kc] = sv[0]; ws_bidx[b * 16 + kc] = si[0]; }
}

// ---------------------------------------------------------------------------
// Finalize: ||x_b||^2 (exact fp32), pick best of 16 chunks, outputs, usage.
// ---------------------------------------------------------------------------
__global__ __launch_bounds__(256) void finalize_k(
    const float* __restrict__ latent, const float* __restrict__ ws_bscore,
    const int* __restrict__ ws_bidx, const float* __restrict__ usage_in,
    float* __restrict__ out_idx, float* __restrict__ out_mind,
    float* __restrict__ out_usage, int* __restrict__ ws_idx)
{
    const int b = blockIdx.x, tid = threadIdx.x;
    __shared__ float sv[256];

    float s = 0.f;
    const float4* lf4 = (const float4*)(latent + (size_t)b * D);
    for (int i = tid; i < D / 4; i += 256) {
        const float4 v = lf4[i];
        s += v.x * v.x + v.y * v.y + v.z * v.z + v.w * v.w;
    }
    sv[tid] = s;
    __syncthreads();
    for (int off = 128; off > 0; off >>= 1) {
        if (tid < off) sv[tid] += sv[tid + off];
        __syncthreads();
    }
    if (tid == 0) {
        const float x2 = sv[0];
        float best = ws_bscore[b * 16];
        int   bi   = ws_bidx[b * 16];
        for (int kc = 1; kc < 16; kc++) {
            const float v = ws_bscore[b * 16 + kc];
            if (v < best) { best = v; bi = ws_bidx[b * 16 + kc]; }  // ties -> lower kc
        }
        out_mind[b] = sqrtf(fmaxf(x2 + best, 0.f));
        out_idx[b]  = (float)bi;
        ws_idx[b]   = bi;
    }
    if (tid < 64) out_usage[b * 64 + tid] = usage_in[b * 64 + tid];
}

// ---------------------------------------------------------------------------
// Gather quantized rows (4 blocks per b) + usage scatter-add.
// ---------------------------------------------------------------------------
__global__ __launch_bounds__(256) void gather_k(
    const float* __restrict__ codebook, const int* __restrict__ ws_idx,
    float* __restrict__ out_q, float* __restrict__ out_usage)
{
    const int b = blockIdx.x, part = blockIdx.y, tid = threadIdx.x;
    const int k = ws_idx[b];
    const int n4 = D / 4 / 4;  // 2000 float4 per part
    const float4* src = (const float4*)(codebook + (size_t)k * D) + part * n4;
    float4*       dst = (float4*)(out_q + (size_t)b * D) + part * n4;
    for (int i = tid; i < n4; i += 256) dst[i] = src[i];
    if (part == 0 && tid == 0) atomicAdd(out_usage + k, 1.0f);
}

extern "C" void kernel_launch(void* const* d_in, const int* in_sizes, int n_in,
                              void* d_out, int out_size, void* d_ws, size_t ws_size,
                              hipStream_t stream)
{
    const float* latent   = (const float*)d_in[0];
    const float* codebook = (const float*)d_in[1];
    const float* usage    = (const float*)d_in[2];

    float* out_q     = (float*)d_out;                       // 64*32000
    float* out_idx   = out_q + (size_t)BNUM * D;            // 64
    float* out_mind  = out_idx + BNUM;                      // 64
    float* out_usage = out_mind + BNUM;                     // 4096

    // ws: afmt (8.19 MB) | ws_xc | ws_c2 | bscore/bidx | idx
    const size_t need20 = AFMT_BYTES +
        ((size_t)20 * BNUM * KNUM + KNUM + 16 * BNUM * 2 + BNUM) * 4 + 256;
    const int dsplit = (ws_size >= need20) ? 20 : 4;

    unsigned short* afmt = (unsigned short*)d_ws;
    float* ws_xc     = (float*)((char*)d_ws + AFMT_BYTES);
    float* ws_c2     = ws_xc + (size_t)dsplit * BNUM * KNUM;
    float* ws_bscore = ws_c2 + KNUM;
    int*   ws_bidx   = (int*)(ws_bscore + 16 * BNUM);
    int*   ws_idx    = ws_bidx + 16 * BNUM;

    hipMemsetAsync(ws_c2, 0, KNUM * sizeof(float), stream);
    conv_latent<<<NSCB * 8 * 64 / 256, 256, 0, stream>>>(latent, afmt);
    if (dsplit == 20) {
        dist_mfma<25><<<dim3(KNUM / TN, 20), 256, 0, stream>>>(codebook, afmt, ws_xc, ws_c2);
        argmin_part<20><<<dim3(BNUM, 16), 256, 0, stream>>>(ws_xc, ws_c2, ws_bscore, ws_bidx);
    } else {
        dist_mfma<125><<<dim3(KNUM / TN, 4), 256, 0, stream>>>(codebook, afmt, ws_xc, ws_c2);
        argmin_part<4><<<dim3(BNUM, 16), 256, 0, stream>>>(ws_xc, ws_c2, ws_bscore, ws_bidx);
    }
    finalize_k<<<BNUM, 256, 0, stream>>>(latent, ws_bscore, ws_bidx, usage,
                                         out_idx, out_mind, out_usage, ws_idx);
    gather_k<<<dim3(BNUM, 4), 256, 0, stream>>>(codebook, ws_idx, out_q, out_usage);
}